// Round 6
// baseline (620.931 us; speedup 1.0000x reference)
//
#include <hip/hip_runtime.h>
#include <cstdint>

// Problem constants: features (B=4, C=256, H=64, W=64) fp32,
// rois (N=2000, 5) fp32, output (N, C, 7, 7) fp32.
constexpr int CCH = 256;
constexpr int HH  = 64;
constexpr int WW  = 64;
constexpr int OHW = 49;
constexpr float RSCALE = 0.0625f;
constexpr int GRID = 1536;      // 6 blocks/CU x 256 CU, co-resident by construction

// Bit-exact fp32 ops on the coordinate path (xs<64 validity test is the only
// discontinuity in the op).
#define FMUL __fmul_rn
#define FADD __fadd_rn
#define FSUB __fsub_rn
#define FDIV __fdiv_rn

typedef float     v4f __attribute__((ext_vector_type(4)));
typedef _Float16  h2  __attribute__((ext_vector_type(2)));
typedef _Float16  h4  __attribute__((ext_vector_type(4)));

__device__ __forceinline__ h2 pkrtz(float a, float b) {   // v_cvt_pkrtz_f16_f32
  auto t = __builtin_amdgcn_cvt_pkrtz(a, b);
  union { decltype(t) s; h2 d; } c; c.s = t; return c.d;
}
__device__ __forceinline__ h4 bcast4(float a) {           // (a,a,a,a) in fp16
  h2 t = pkrtz(a, a);
  return __builtin_shufflevector(t, t, 0, 1, 0, 1);
}
__device__ __forceinline__ h4 u2h(uint2 u) {              // reinterpret 4xfp16
  union { uint2 u; h4 h; } c; c.u = u; return c.h;
}
__device__ __forceinline__ h4 h4max(h4 a, h4 b) {         // 2x v_pk_max_f16
  return __builtin_elementwise_max(a, b);
}

// ---------------------------------------------------------------------------
// r15: ONE dispatch, barrier v2. r14 passed (fused logic + cross-XCD
// visibility protocol correct) but ran 281us: the single-counter fetch_add
// serialized 1024 cross-XCD RMWs on one cacheline (~275ns each ~= 281us
// measured, VALU 3.8% / HBM 5% / occ 47% = everyone parked).
// Barrier v2 (distributed arrivals):
//  - each block release-stores its OWN slot (128B stride, zero contention,
//    arrivals fully parallel);
//  - aggregator block (GRID-1) polls slots with 256 parallel acquire loads +
//    LDS reduce; on complete, release-stores a flag;
//  - waiters poll flag with s_sleep(32).
//  HB chain: X rel-store slot -> agg acq-load -> agg rel-store flag ->
//  waiter acq-load  => all X's featbf/meta writes visible to all waiters.
// Grid 1536 @ __launch_bounds__(256,6): VGPR<=85 (r14 measured 44), LDS
// 25.1KB -> 6 blk/CU co-resident guaranteed; 1536%8==0 keeps XCD affinity.
// Phases (unchanged from r14):
//   1a: transpose+quantize (B,C,HW) f32 -> (B,HW,C) fp16; 1 tile/block
//       (blocks >=1024 have no tile, arrive immediately).
//   1b: block 0: scan-based sched (no LDS atomics).
//   barrier v2
//   2:  r11 roi body, persistent stride GRID.
// meta: [0..13]=cnt/off/slack(+spare); perm[N]; extra[N];
//       barstate[32 + GRID*32] ints (flag @ +0, slot b @ 32+b*32), zeroed
//       per replay by hipMemsetAsync.
// ---------------------------------------------------------------------------
__global__ __launch_bounds__(256, 6) void fused_kernel(
    const float* __restrict__ in, unsigned short* __restrict__ featbf,
    const float* __restrict__ rois, int N, int M, int slots_, int use_perm,
    int B, int* __restrict__ meta, float* __restrict__ out) {
  __shared__ __attribute__((aligned(16))) unsigned char lds_raw[25088];
  const int t   = threadIdx.x;
  const int bid = blockIdx.x;

  // ---------------- phase 1a: transpose + quantize ----------------
  {
    float (*tile)[65] = (float (*)[65])lds_raw;          // 16640 B of lds_raw
    for (int tz = bid; tz < B * 256; tz += (int)gridDim.x) {
      const int b  = tz >> 8;
      const int c0 = ((tz >> 6) & 3) * 64;
      const int s0 = (tz & 63) * 64;
      const float* inb = in + (size_t)b * CCH * (HH * WW);
      unsigned short* outb = featbf + (size_t)b * (HH * WW) * CCH;
      const int cl = t >> 4, sq = t & 15;
#pragma unroll
      for (int k = 0; k < 4; ++k) {
        const int c = cl + 16 * k;
        const v4f v = __builtin_nontemporal_load(
            (const v4f*)(inb + (size_t)(c0 + c) * (HH * WW) + s0 + 4 * sq));
        tile[c][4 * sq + 0] = v[0];
        tile[c][4 * sq + 1] = v[1];
        tile[c][4 * sq + 2] = v[2];
        tile[c][4 * sq + 3] = v[3];
      }
      __syncthreads();
      const int cq = t & 15, rl = t >> 4;
#pragma unroll
      for (int k = 0; k < 4; ++k) {
        const int r = rl + 16 * k;
        union { h2 h; unsigned u; } p0, p1;
        p0.h.x = (_Float16)tile[4 * cq + 0][r];          // v_cvt_f16_f32 (RNE)
        p0.h.y = (_Float16)tile[4 * cq + 1][r];
        p1.h.x = (_Float16)tile[4 * cq + 2][r];
        p1.h.y = (_Float16)tile[4 * cq + 3][r];
        uint2 w; w.x = p0.u; w.y = p1.u;
        *(uint2*)(outb + (size_t)(s0 + r) * CCH + c0 + 4 * cq) = w;
      }
      __syncthreads();                                   // LDS reuse safe
    }
  }

  // ---------------- phase 1b: scan-based sched (block 0) ----------------
  if (use_perm && bid == 0) {
    int4* sc = (int4*)lds_raw;                           // 256 x int4 = 4 KB
    int k0[4] = {0, 0, 0, 0};
    int keys[8];
    const int base = t * 8;                              // 256*8 = 2048 >= N
#pragma unroll
    for (int e = 0; e < 8; ++e) {
      const int i = base + e;
      int key = 4;
      if (i < N) { key = (int)rois[i * 5]; k0[key]++; }
      keys[e] = key;
    }
    sc[t] = make_int4(k0[0], k0[1], k0[2], k0[3]);
    __syncthreads();
    for (int d = 1; d < 256; d <<= 1) {                  // Hillis-Steele scan
      const int4 v = sc[t];
      const int4 u = (t >= d) ? sc[t - d] : make_int4(0, 0, 0, 0);
      __syncthreads();
      sc[t] = make_int4(v.x + u.x, v.y + u.y, v.z + u.z, v.w + u.w);
      __syncthreads();
    }
    const int4 incl = sc[t];
    const int4 tot  = sc[255];
    const int cnt_[4] = {tot.x, tot.y, tot.z, tot.w};
    int off_[4];
    off_[0] = 0; off_[1] = cnt_[0]; off_[2] = off_[1] + cnt_[1]; off_[3] = off_[2] + cnt_[2];
    int rank[4] = {off_[0] + incl.x - k0[0], off_[1] + incl.y - k0[1],
                   off_[2] + incl.z - k0[2], off_[3] + incl.w - k0[3]};
    int* perm = meta + 16;
#pragma unroll
    for (int e = 0; e < 8; ++e) {
      const int key = keys[e];
      if (key < 4) perm[rank[key]++] = base + e;
    }
    if (t == 0) {
      int cs = 0;
      for (int p = 0; p < 4; ++p) {
        meta[p] = cnt_[p]; meta[4 + p] = off_[p]; meta[8 + p] = cs;
        if (slots_ - cnt_[p] > 0) cs += slots_ - cnt_[p];
      }
    }
    __syncthreads();                                     // perm complete
    int* extra = meta + 16 + N;
    int exbase = 0;
    for (int p = 0; p < 4; ++p) {
      const int ex = cnt_[p] - slots_;
      for (int e = t; e < ex; e += 256) extra[exbase + e] = perm[off_[p] + slots_ + e];
      if (ex > 0) exbase += ex;
    }
  }

  // ---------------- software grid barrier v2 (distributed arrivals) -------
  {
    int* barstate   = meta + 16 + 2 * N;       // zeroed each replay
    unsigned* flag  = (unsigned*)barstate;
    unsigned* slots = (unsigned*)(barstate + 32);
    __threadfence();                           // release: writeback featbf/meta
    __syncthreads();
    if (t == 0)
      __hip_atomic_store(&slots[(unsigned)bid * 32], 1u, __ATOMIC_RELEASE,
                         __HIP_MEMORY_SCOPE_AGENT);
    if (bid == (int)gridDim.x - 1) {
      // aggregator: 256 threads poll 6 slots each, LDS-reduce
      __shared__ unsigned acc;
      for (;;) {
        if (t == 0) acc = 0;
        __syncthreads();
        unsigned s = 0;
        for (int k = t; k < (int)gridDim.x; k += 256)
          s += __hip_atomic_load(&slots[(unsigned)k * 32], __ATOMIC_ACQUIRE,
                                 __HIP_MEMORY_SCOPE_AGENT);
        atomicAdd(&acc, s);
        __syncthreads();
        if (acc == (unsigned)gridDim.x) break;
        __builtin_amdgcn_s_sleep(8);
      }
      __threadfence();
      if (t == 0)
        __hip_atomic_store(flag, 1u, __ATOMIC_RELEASE, __HIP_MEMORY_SCOPE_AGENT);
    } else {
      if (t == 0) {
        while (!__hip_atomic_load(flag, __ATOMIC_ACQUIRE, __HIP_MEMORY_SCOPE_AGENT))
          __builtin_amdgcn_s_sleep(32);
      }
    }
    __syncthreads();
    __threadfence();                           // acquire: drop stale L1/L2 views
  }

  // ---------------- phase 2: roi align + maxpool (r11 body) ----------------
  h4*       ldsA = (h4*)lds_raw;                         // 12544 B
  _Float16* ldsC = (_Float16*)(lds_raw + 12544);         // 12544 B
  const uint2* feat = (const uint2*)featbf;
  const int g = t & 31;                                  // granule (4 ch)
  const int r = t >> 5;                                  // sample row 0..7

  const int c0_ = use_perm ? meta[0] : 0;                // uniform meta loads
  const int c1_ = use_perm ? meta[1] : 0;
  const int c2_ = use_perm ? meta[2] : 0;
  const int c3_ = use_perm ? meta[3] : 0;
  const int o0_ = use_perm ? meta[4] : 0, o1_ = use_perm ? meta[5] : 0;
  const int o2_ = use_perm ? meta[6] : 0, o3_ = use_perm ? meta[7] : 0;
  const int s0_ = use_perm ? meta[8] : 0, s1_ = use_perm ? meta[9] : 0;
  const int s2_ = use_perm ? meta[10] : 0, s3_ = use_perm ? meta[11] : 0;
  const int* perm  = meta + 16;
  const int* extra = meta + 16 + N;

  for (int i = bid; i < M; i += (int)gridDim.x) {
    int n, half;
    if (use_perm) {
      const int p = (i & 7) >> 1;
      half        = i & 1;
      const int s = i >> 3;
      const int c_ = p == 0 ? c0_ : (p == 1 ? c1_ : (p == 2 ? c2_ : c3_));
      const int o_ = p == 0 ? o0_ : (p == 1 ? o1_ : (p == 2 ? o2_ : o3_));
      const int sl = p == 0 ? s0_ : (p == 1 ? s1_ : (p == 2 ? s2_ : s3_));
      n = (s < c_) ? perm[o_ + s] : extra[sl + (s - c_)];
    } else {
      n = i >> 1; half = i & 1;
    }

    const float rb = rois[n * 5 + 0];
    const float x1 = FMUL(rois[n * 5 + 1], RSCALE);
    const float y1 = FMUL(rois[n * 5 + 2], RSCALE);
    const float x2 = FMUL(rois[n * 5 + 3], RSCALE);
    const float y2 = FMUL(rois[n * 5 + 4], RSCALE);
    const int   b  = (int)rb;
    const float bh = FDIV(FSUB(y2, y1), 7.0f);
    const float bw = FDIV(FSUB(x2, x1), 7.0f);

    int   xo0[8], xo1[8];
    float lx[8];
    bool  xv[8];
#pragma unroll
    for (int q = 0; q < 8; ++q) {
      const float xs = FADD(x1, FMUL(bw, (float)q));
      xv[q] = (xs >= 0.0f) && (xs < (float)WW);
      const float xf = floorf(xs);
      lx[q] = FSUB(xs, xf);
      int a = (int)xf;
      a = a < 0 ? 0 : (a > WW - 1 ? WW - 1 : a);
      xo0[q] = a * (CCH / 4);
      xo1[q] = ((a + 1 > WW - 1) ? WW - 1 : a + 1) * (CCH / 4);
    }

    const float ys = FADD(y1, FMUL(bh, (float)r));
    const bool  yv = (ys >= 0.0f) && (ys < (float)HH);
    const float yf = floorf(ys);
    const float ly = FSUB(ys, yf);
    int d = (int)yf;
    d = d < 0 ? 0 : (d > HH - 1 ? HH - 1 : d);
    const int d1 = (d + 1 > HH - 1) ? HH - 1 : d + 1;

    const uint2* fb = feat + (size_t)b * (HH * WW) * (CCH / 4) + (half * 32 + g);
    const uint2* r0 = fb + (size_t)d  * (WW * (CCH / 4));
    const uint2* r1 = fb + (size_t)d1 * (WW * (CCH / 4));
    const float wy1 = ly, wy0 = 1.0f - ly;

    h4 hc[7], vprev;
#pragma unroll
    for (int h = 0; h < 2; ++h) {
      uint2 g00[4], g01[4], g10[4], g11[4];
#pragma unroll
      for (int q = 0; q < 4; ++q) {
        const int s = 4 * h + q;
        g00[q] = r0[xo0[s]];
        g01[q] = r0[xo1[s]];
        g10[q] = r1[xo0[s]];
        g11[q] = r1[xo1[s]];
      }
      h4 v[4];
#pragma unroll
      for (int q = 0; q < 4; ++q) {
        const int s = 4 * h + q;
        const bool ok = yv && xv[s];
        const float wx1 = lx[s], wx0 = 1.0f - wx1;
        const h4 w00 = bcast4(wy0 * wx0);    // f32 product, 1 rounding to fp16
        const h4 w01 = bcast4(wy0 * wx1);
        const h4 w10 = bcast4(wy1 * wx0);
        const h4 w11 = bcast4(wy1 * wx1);
        h4 rr = w00 * u2h(g00[q]) + w01 * u2h(g01[q])
              + w10 * u2h(g10[q]) + w11 * u2h(g11[q]);   // v_pk_{mul,fma}_f16
        v[q] = ok ? rr : h4{};
      }
      if (h == 0) {
        hc[0] = h4max(v[0], v[1]);
        hc[1] = h4max(v[1], v[2]);
        hc[2] = h4max(v[2], v[3]);
        vprev = v[3];
      } else {
        hc[3] = h4max(vprev, v[0]);
        hc[4] = h4max(v[0], v[1]);
        hc[5] = h4max(v[1], v[2]);
        hc[6] = h4max(v[2], v[3]);
      }
    }

    // ---- phase A: row r>=1 publishes hc at slot r-1 (ds_write_b64) ----
    if (r >= 1) {
#pragma unroll
      for (int m = 0; m < 7; ++m)
        ldsA[((r - 1) * 7 + m) * 32 + g] = hc[m];
    }
    __syncthreads();                         // bar1: A->B publish
                                             //       (also orders D(k-1) vs C(k))

    // ---- phase B+C fused: pk_max with row r+1, scatter to fp16 out-image ----
    if (r <= 6) {
      _Float16* cb = ldsC + (4 * g) * OHW + r * 7;   // channel 4g, out row r
#pragma unroll
      for (int m = 0; m < 7; ++m) {
        const h4 x = h4max(hc[m], ldsA[(r * 7 + m) * 32 + g]);
        cb[0 * OHW + m] = x[0];
        cb[1 * OHW + m] = x[1];
        cb[2 * OHW + m] = x[2];
        cb[3 * OHW + m] = x[3];
      }
    }
    __syncthreads();                         // bar2: C->D writeback
                                             //       (also orders B(k) vs A(k+1))

    // ---- phase D: contiguous b64 read -> 4x cvt -> nontemporal dwordx4.
    //      1568 float4 over 256 threads: 6 full iters + 32-lane tail. ----
    const uint2* cs = (const uint2*)ldsC;
    v4f* o4 = (v4f*)(out + (size_t)n * (CCH * OHW) + half * (CCH / 2) * OHW);
#pragma unroll
    for (int m = 0; m < 7; ++m) {
      const int idx = m * 256 + t;
      if (m < 6 || t < 32) {
        const uint2 qv = cs[idx];
        union { unsigned u; h2 h; } e0, e1;
        e0.u = qv.x; e1.u = qv.y;
        v4f wv;
        wv.x = (float)e0.h.x;
        wv.y = (float)e0.h.y;
        wv.z = (float)e1.h.x;
        wv.w = (float)e1.h.y;
        __builtin_nontemporal_store(wv, o4 + idx);
      }
    }
  }
}

// ---------------------------------------------------------------------------
// Fallback (workspace too small): round-2 scalar path, known-correct.
// ---------------------------------------------------------------------------
__global__ __launch_bounds__(256) void roi_kernel_fb(const float* __restrict__ feat,
                                                     const float* __restrict__ rois,
                                                     float* __restrict__ out) {
  __shared__ float sout[CCH * OHW];
  const int n = blockIdx.x;
  const int c = threadIdx.x;

  const float rb = rois[n * 5 + 0];
  const float x1 = FMUL(rois[n * 5 + 1], RSCALE);
  const float y1 = FMUL(rois[n * 5 + 2], RSCALE);
  const float x2 = FMUL(rois[n * 5 + 3], RSCALE);
  const float y2 = FMUL(rois[n * 5 + 4], RSCALE);
  const int b = (int)rb;
  const float bh = FDIV(FSUB(y2, y1), 7.0f);
  const float bw = FDIV(FSUB(x2, x1), 7.0f);

  int ix0[8], ix1[8], iy0[8], iy1[8];
  float lx[8], ly[8];
  bool xv[8], yv[8];
#pragma unroll
  for (int i = 0; i < 8; ++i) {
    const float xs = FADD(x1, FMUL(bw, (float)i));
    const float ys = FADD(y1, FMUL(bh, (float)i));
    xv[i] = (xs >= 0.0f) && (xs < (float)WW);
    yv[i] = (ys >= 0.0f) && (ys < (float)HH);
    const float xf = floorf(xs);
    const float yf = floorf(ys);
    lx[i] = FSUB(xs, xf);
    ly[i] = FSUB(ys, yf);
    int a = (int)xf;
    a = a < 0 ? 0 : (a > WW - 1 ? WW - 1 : a);
    ix0[i] = a;
    ix1[i] = (a + 1 > WW - 1) ? WW - 1 : a + 1;
    int d = (int)yf;
    d = d < 0 ? 0 : (d > HH - 1 ? HH - 1 : d);
    iy0[i] = d;
    iy1[i] = (d + 1 > HH - 1) ? HH - 1 : d + 1;
  }

  const float* fbp = feat + ((size_t)b * CCH + c) * (size_t)(HH * WW);
  float hp[7];
#pragma unroll
  for (int j = 0; j < 8; ++j) {
    float v[8];
    const float wy1 = ly[j], wy0 = 1.0f - ly[j];
#pragma unroll
    for (int i = 0; i < 8; ++i) {
      if (yv[j] && xv[i]) {
        const float f00 = fbp[iy0[j] * WW + ix0[i]];
        const float f01 = fbp[iy0[j] * WW + ix1[i]];
        const float f10 = fbp[iy1[j] * WW + ix0[i]];
        const float f11 = fbp[iy1[j] * WW + ix1[i]];
        const float wx1 = lx[i], wx0 = 1.0f - wx1;
        v[i] = wy0 * (wx0 * f00 + wx1 * f01) + wy1 * (wx0 * f10 + wx1 * f11);
      } else {
        v[i] = 0.0f;
      }
    }
    float hc[7];
#pragma unroll
    for (int i = 0; i < 7; ++i) hc[i] = fmaxf(v[i], v[i + 1]);
    if (j > 0) {
#pragma unroll
      for (int i = 0; i < 7; ++i)
        sout[c * OHW + (j - 1) * 7 + i] = fmaxf(hp[i], hc[i]);
    }
#pragma unroll
    for (int i = 0; i < 7; ++i) hp[i] = hc[i];
  }
  __syncthreads();
  const float4* s4 = (const float4*)sout;
  float4* o4 = (float4*)(out + (size_t)n * (CCH * OHW));
  for (int q = c; q < (CCH * OHW) / 4; q += 256) o4[q] = s4[q];
}

extern "C" void kernel_launch(void* const* d_in, const int* in_sizes, int n_in,
                              void* d_out, int out_size, void* d_ws, size_t ws_size,
                              hipStream_t stream) {
  (void)n_in; (void)out_size;
  const float* feat = (const float*)d_in[0];
  const float* rois = (const float*)d_in[1];
  float* out = (float*)d_out;
  const int N = in_sizes[1] / 5;
  const int B = in_sizes[0] / (CCH * HH * WW);
  const int M = 2 * N;                                  // roi items (2/roi)
  const size_t featbf_bytes = (size_t)in_sizes[0] * sizeof(unsigned short);
  const size_t bar_ints     = (size_t)(32 + GRID * 32); // flag + padded slots
  const size_t meta_bytes   = ((size_t)(16 + 2 * N) + bar_ints) * sizeof(int);

  if (ws_size >= featbf_bytes + meta_bytes && N <= 2048 && B == 4 && (M & 7) == 0) {
    unsigned short* featbf = (unsigned short*)d_ws;
    int* meta = (int*)((char*)d_ws + featbf_bytes);
    const int use_perm = 1;
    const int slots = M >> 3;

    // Zero the barrier state (flag + arrival slots) each replay.
    // Graph-capturable; immune to workspace re-poisoning between replays.
    hipMemsetAsync((void*)(meta + 16 + 2 * N), 0, bar_ints * sizeof(int), stream);

    // GRID=1536 blocks: co-resident by construction (LDS 25.1KB -> 6/CU cap;
    // launch_bounds(256,6) -> VGPR<=85, r14 measured 44; 6*256CU = 1536).
    fused_kernel<<<dim3(GRID), dim3(256), 0, stream>>>(
        feat, featbf, rois, N, M, slots, use_perm, B, meta, out);
  } else {
    roi_kernel_fb<<<dim3(N), dim3(256), 0, stream>>>(feat, rois, out);
  }
}

// Round 8
// 134.158 us; speedup vs baseline: 4.6283x; 4.6283x over previous
//
#include <hip/hip_runtime.h>
#include <cstdint>

// Problem constants: features (B=4, C=256, H=64, W=64) fp32,
// rois (N=2000, 5) fp32, output (N, C, 7, 7) fp32.
constexpr int CCH = 256;
constexpr int HH  = 64;
constexpr int WW  = 64;
constexpr int OHW = 49;
constexpr float RSCALE = 0.0625f;

// Bit-exact fp32 ops on the coordinate path (xs<64 validity test is the only
// discontinuity in the op).
#define FMUL __fmul_rn
#define FADD __fadd_rn
#define FSUB __fsub_rn
#define FDIV __fdiv_rn

typedef float     v4f __attribute__((ext_vector_type(4)));
typedef _Float16  h2  __attribute__((ext_vector_type(2)));
typedef _Float16  h4  __attribute__((ext_vector_type(4)));

__device__ __forceinline__ h2 pkrtz(float a, float b) {   // v_cvt_pkrtz_f16_f32
  auto t = __builtin_amdgcn_cvt_pkrtz(a, b);
  union { decltype(t) s; h2 d; } c; c.s = t; return c.d;
}
__device__ __forceinline__ h4 bcast4(float a) {           // (a,a,a,a) in fp16
  h2 t = pkrtz(a, a);
  return __builtin_shufflevector(t, t, 0, 1, 0, 1);
}
__device__ __forceinline__ h4 u2h(uint2 u) {              // reinterpret 4xfp16
  union { uint2 u; h4 h; } c; c.u = u; return c.h;
}
__device__ __forceinline__ h4 h4max(h4 a, h4 b) {         // 2x v_pk_max_f16
  return __builtin_elementwise_max(a, b);
}

// ---------------------------------------------------------------------------
// Kernel 1 (fused): transpose+quantize features (B,C,H*W) f32 -> (B,H*W,C)
// fp16, PLUS the roi scheduling pass as one extra grid slice (z==B, block
// (0,0)). Identical to the r2 champion.
// r16 scheduling (1 block/roi): block i -> XCD i%8; batch p=(i&7)>>1 (two
// XCDs per batch, 2.1MB fp16 slice < 4MiB XCD L2); slot s=(i>>3)*2+(i&1),
// slots/batch = N/4.
// meta: [0..3]=cnt [4..7]=off [8..11]=cumslack; perm[N]; extra[N].
// ---------------------------------------------------------------------------
__global__ __launch_bounds__(256) void ktrans_sched(const float* __restrict__ in,
                                                    unsigned short* __restrict__ out,
                                                    const float* __restrict__ rois,
                                                    int N, int slots, int do_sched,
                                                    int B, int* __restrict__ meta) {
  const int t = threadIdx.x;

  if ((int)blockIdx.z == B) {
    if (blockIdx.x != 0 || blockIdx.y != 0 || !do_sched) return;
    __shared__ int cnt[4], rnk[4], off[4], slack[4], excess[4];
    if (t < 4) { cnt[t] = 0; rnk[t] = 0; }
    __syncthreads();
    for (int i = t; i < N; i += 256) atomicAdd(&cnt[(int)rois[i * 5]], 1);
    __syncthreads();
    if (t == 0) {
      int o = 0, cs = 0, ce = 0;
      for (int p = 0; p < 4; ++p) {
        off[p] = o; o += cnt[p];
        slack[p]  = cs; if (slots - cnt[p] > 0) cs += slots - cnt[p];
        excess[p] = ce; if (cnt[p] - slots > 0) ce += cnt[p] - slots;
        meta[p] = cnt[p]; meta[4 + p] = off[p]; meta[8 + p] = slack[p];
      }
    }
    __syncthreads();
    int* perm = meta + 16;
    for (int i = t; i < N; i += 256) {
      const int b = (int)rois[i * 5];
      perm[off[b] + atomicAdd(&rnk[b], 1)] = i;
    }
    __syncthreads();
    int* extra = meta + 16 + N;
    for (int p = 0; p < 4; ++p) {
      const int ex = cnt[p] - slots;
      for (int e = t; e < ex; e += 256) extra[excess[p] + e] = perm[off[p] + slots + e];
    }
    return;
  }

  __shared__ float tile[64][65];
  const int b  = blockIdx.z;
  const int c0 = blockIdx.y * 64;
  const int s0 = blockIdx.x * 64;
  const float* inb = in + (size_t)b * CCH * (HH * WW);
  unsigned short* outb = out + (size_t)b * (HH * WW) * CCH;

  const int cl = t >> 4, sq = t & 15;
#pragma unroll
  for (int k = 0; k < 4; ++k) {
    const int c = cl + 16 * k;
    const v4f v = __builtin_nontemporal_load(
        (const v4f*)(inb + (size_t)(c0 + c) * (HH * WW) + s0 + 4 * sq));
    tile[c][4 * sq + 0] = v[0];
    tile[c][4 * sq + 1] = v[1];
    tile[c][4 * sq + 2] = v[2];
    tile[c][4 * sq + 3] = v[3];
  }
  __syncthreads();
  const int cq = t & 15, rl = t >> 4;
#pragma unroll
  for (int k = 0; k < 4; ++k) {
    const int r = rl + 16 * k;
    union { h2 h; unsigned u; } p0, p1;
    p0.h.x = (_Float16)tile[4 * cq + 0][r];   // v_cvt_f16_f32 (RNE)
    p0.h.y = (_Float16)tile[4 * cq + 1][r];
    p1.h.x = (_Float16)tile[4 * cq + 2][r];
    p1.h.y = (_Float16)tile[4 * cq + 3][r];
    uint2 w; w.x = p0.u; w.y = p1.u;
    *(uint2*)(outb + (size_t)(s0 + r) * CCH + c0 + 4 * cq) = w;
  }
}

// ---------------------------------------------------------------------------
// Kernel 2 (r16): RoIAlign + 2x2 s1 maxpool, packed-fp16 datapath.
// ONE 512-thread block per roi (was 2x256). Halves per-roi overhead that the
// r11/r12 ablations showed is the only thing left moving: roi/perm decode
// chains (2 -> 1), coordinate math duplication, barriers per roi (4 -> 2),
// block count (4000 -> 2000). Output write per block is now one 50KB fully
// contiguous nontemporal stream.
// Thread map: half = t>>8, tt = t&255, g = tt&31 (4-ch granule), r = tt>>5.
// LDS: ldsA h4[49*64] (25088B, halves interleaved in granule dim) +
//      ldsC fp16[256*49] (25088B, channel-major out image) = 50176B
//      -> 3 blocks/CU x 8 waves = 24 waves/CU (same residency as r2).
// __launch_bounds__(512,6): 6 waves/EU -> VGPR cap 85; measured 44 (r14).
// Barrier legality: bar1 orders A(publish hc, cross-wave) -> B(read r+1's
// hc); B->C same-thread, ldsA/ldsC disjoint; bar2 orders C -> D readback.
// ---------------------------------------------------------------------------
__global__ __launch_bounds__(512, 6) void roi_kernel16(const uint2* __restrict__ feat,
                                                       const float* __restrict__ rois,
                                                       const int* __restrict__ meta,
                                                       int N, int use_perm,
                                                       float* __restrict__ out) {
  __shared__ __attribute__((aligned(16))) h4       ldsA[OHW * 64];          // 25088 B
  __shared__ __attribute__((aligned(16))) _Float16 ldsC[CCH * OHW];         // 25088 B
  const int i  = blockIdx.x;
  const int t  = threadIdx.x;
  const int half = t >> 8;                     // feature half 0/1 (128 ch)
  const int tt = t & 255;
  const int g  = tt & 31;                      // granule within half (4 ch)
  const int r  = tt >> 5;                      // sample row 0..7

  int n;
  if (use_perm) {
    const int p = (i & 7) >> 1;                // batch affinity (2 XCDs/batch)
    const int s = ((i >> 3) << 1) | (i & 1);   // slot within batch, [0, N/4)
    const int c_ = meta[p];
    const int o_ = meta[4 + p];
    const int sl = meta[8 + p];
    const int* perm  = meta + 16;
    const int* extra = meta + 16 + N;
    n = (s < c_) ? perm[o_ + s] : extra[sl + (s - c_)];
  } else {
    n = i;
  }

  const float rb = rois[n * 5 + 0];
  const float x1 = FMUL(rois[n * 5 + 1], RSCALE);
  const float y1 = FMUL(rois[n * 5 + 2], RSCALE);
  const float x2 = FMUL(rois[n * 5 + 3], RSCALE);
  const float y2 = FMUL(rois[n * 5 + 4], RSCALE);
  const int   b  = (int)rb;
  const float bh = FDIV(FSUB(y2, y1), 7.0f);
  const float bw = FDIV(FSUB(x2, x1), 7.0f);

  int   xo0[8], xo1[8];
  float lx[8];
  bool  xv[8];
#pragma unroll
  for (int q = 0; q < 8; ++q) {
    const float xs = FADD(x1, FMUL(bw, (float)q));
    xv[q] = (xs >= 0.0f) && (xs < (float)WW);
    const float xf = floorf(xs);
    lx[q] = FSUB(xs, xf);
    int a = (int)xf;
    a = a < 0 ? 0 : (a > WW - 1 ? WW - 1 : a);
    xo0[q] = a * (CCH / 4);
    xo1[q] = ((a + 1 > WW - 1) ? WW - 1 : a + 1) * (CCH / 4);
  }

  const float ys = FADD(y1, FMUL(bh, (float)r));
  const bool  yv = (ys >= 0.0f) && (ys < (float)HH);
  const float yf = floorf(ys);
  const float ly = FSUB(ys, yf);
  int d = (int)yf;
  d = d < 0 ? 0 : (d > HH - 1 ? HH - 1 : d);
  const int d1 = (d + 1 > HH - 1) ? HH - 1 : d + 1;

  const uint2* fb = feat + (size_t)b * (HH * WW) * (CCH / 4) + (half * 32 + g);
  const uint2* r0 = fb + (size_t)d  * (WW * (CCH / 4));
  const uint2* r1 = fb + (size_t)d1 * (WW * (CCH / 4));
  const float wy1 = ly, wy0 = 1.0f - ly;

  h4 hc[7], vprev;
#pragma unroll
  for (int h = 0; h < 2; ++h) {
    uint2 g00[4], g01[4], g10[4], g11[4];
#pragma unroll
    for (int q = 0; q < 4; ++q) {
      const int s = 4 * h + q;
      g00[q] = r0[xo0[s]];
      g01[q] = r0[xo1[s]];
      g10[q] = r1[xo0[s]];
      g11[q] = r1[xo1[s]];
    }
    h4 v[4];
#pragma unroll
    for (int q = 0; q < 4; ++q) {
      const int s = 4 * h + q;
      const bool ok = yv && xv[s];
      const float wx1 = lx[s], wx0 = 1.0f - wx1;
      const h4 w00 = bcast4(wy0 * wx0);        // f32 product, 1 rounding to fp16
      const h4 w01 = bcast4(wy0 * wx1);
      const h4 w10 = bcast4(wy1 * wx0);
      const h4 w11 = bcast4(wy1 * wx1);
      h4 rr = w00 * u2h(g00[q]) + w01 * u2h(g01[q])
            + w10 * u2h(g10[q]) + w11 * u2h(g11[q]);   // 8x v_pk_{mul,fma}_f16
      v[q] = ok ? rr : h4{};
    }
    if (h == 0) {
      hc[0] = h4max(v[0], v[1]);
      hc[1] = h4max(v[1], v[2]);
      hc[2] = h4max(v[2], v[3]);
      vprev = v[3];
    } else {
      hc[3] = h4max(vprev, v[0]);
      hc[4] = h4max(v[0], v[1]);
      hc[5] = h4max(v[1], v[2]);
      hc[6] = h4max(v[2], v[3]);
    }
  }

  // ---- phase A: row r>=1 publishes hc at slot r-1 (ds_write_b64) ----
  if (r >= 1) {
#pragma unroll
    for (int m = 0; m < 7; ++m)
      ldsA[((r - 1) * 7 + m) * 64 + half * 32 + g] = hc[m];
  }
  __syncthreads();                             // bar1: A->B cross-wave publish

  // ---- phase B+C fused: row r<=6 maxes with row r+1's hc (b64 read +
  //      pk_max) and scatters into the fp16 out-linear image with
  //      immediate-offset ds_write_b16. ldsA/ldsC disjoint: no B->C barrier. ----
  if (r <= 6) {
    _Float16* cb = ldsC + (half * 128 + 4 * g) * OHW + r * 7;  // ch, out row r
#pragma unroll
    for (int m = 0; m < 7; ++m) {
      const h4 x = h4max(hc[m], ldsA[(r * 7 + m) * 64 + half * 32 + g]);
      cb[0 * OHW + m] = x[0];
      cb[1 * OHW + m] = x[1];
      cb[2 * OHW + m] = x[2];
      cb[3 * OHW + m] = x[3];
    }
  }
  __syncthreads();                             // bar2: C->D cross-wave writeback

  // ---- phase D: contiguous b64 read -> 4x cvt -> nontemporal dwordx4.
  //      3136 float4 (whole roi, 50KB contiguous) over 512 threads:
  //      6 full iters + 64-lane tail. ----
  const uint2* cs = (const uint2*)ldsC;
  v4f* o4 = (v4f*)(out + (size_t)n * (CCH * OHW));
#pragma unroll
  for (int m = 0; m < 7; ++m) {
    const int idx = m * 512 + t;
    if (m < 6 || t < 64) {
      const uint2 qv = cs[idx];
      union { unsigned u; h2 h; } e0, e1;
      e0.u = qv.x; e1.u = qv.y;
      v4f wv;
      wv.x = (float)e0.h.x;
      wv.y = (float)e0.h.y;
      wv.z = (float)e1.h.x;
      wv.w = (float)e1.h.y;
      __builtin_nontemporal_store(wv, o4 + idx);
    }
  }
}

// ---------------------------------------------------------------------------
// Fallback (workspace too small): round-2 scalar path, known-correct.
// ---------------------------------------------------------------------------
__global__ __launch_bounds__(256) void roi_kernel_fb(const float* __restrict__ feat,
                                                     const float* __restrict__ rois,
                                                     float* __restrict__ out) {
  __shared__ float sout[CCH * OHW];
  const int n = blockIdx.x;
  const int c = threadIdx.x;

  const float rb = rois[n * 5 + 0];
  const float x1 = FMUL(rois[n * 5 + 1], RSCALE);
  const float y1 = FMUL(rois[n * 5 + 2], RSCALE);
  const float x2 = FMUL(rois[n * 5 + 3], RSCALE);
  const float y2 = FMUL(rois[n * 5 + 4], RSCALE);
  const int b = (int)rb;
  const float bh = FDIV(FSUB(y2, y1), 7.0f);
  const float bw = FDIV(FSUB(x2, x1), 7.0f);

  int ix0[8], ix1[8], iy0[8], iy1[8];
  float lx[8], ly[8];
  bool xv[8], yv[8];
#pragma unroll
  for (int i = 0; i < 8; ++i) {
    const float xs = FADD(x1, FMUL(bw, (float)i));
    const float ys = FADD(y1, FMUL(bh, (float)i));
    xv[i] = (xs >= 0.0f) && (xs < (float)WW);
    yv[i] = (ys >= 0.0f) && (ys < (float)HH);
    const float xf = floorf(xs);
    const float yf = floorf(ys);
    lx[i] = FSUB(xs, xf);
    ly[i] = FSUB(ys, yf);
    int a = (int)xf;
    a = a < 0 ? 0 : (a > WW - 1 ? WW - 1 : a);
    ix0[i] = a;
    ix1[i] = (a + 1 > WW - 1) ? WW - 1 : a + 1;
    int d = (int)yf;
    d = d < 0 ? 0 : (d > HH - 1 ? HH - 1 : d);
    iy0[i] = d;
    iy1[i] = (d + 1 > HH - 1) ? HH - 1 : d + 1;
  }

  const float* fbp = feat + ((size_t)b * CCH + c) * (size_t)(HH * WW);
  float hp[7];
#pragma unroll
  for (int j = 0; j < 8; ++j) {
    float v[8];
    const float wy1 = ly[j], wy0 = 1.0f - ly[j];
#pragma unroll
    for (int i = 0; i < 8; ++i) {
      if (yv[j] && xv[i]) {
        const float f00 = fbp[iy0[j] * WW + ix0[i]];
        const float f01 = fbp[iy0[j] * WW + ix1[i]];
        const float f10 = fbp[iy1[j] * WW + ix0[i]];
        const float f11 = fbp[iy1[j] * WW + ix1[i]];
        const float wx1 = lx[i], wx0 = 1.0f - wx1;
        v[i] = wy0 * (wx0 * f00 + wx1 * f01) + wy1 * (wx0 * f10 + wx1 * f11);
      } else {
        v[i] = 0.0f;
      }
    }
    float hc[7];
#pragma unroll
    for (int i = 0; i < 7; ++i) hc[i] = fmaxf(v[i], v[i + 1]);
    if (j > 0) {
#pragma unroll
      for (int i = 0; i < 7; ++i)
        sout[c * OHW + (j - 1) * 7 + i] = fmaxf(hp[i], hc[i]);
    }
#pragma unroll
    for (int i = 0; i < 7; ++i) hp[i] = hc[i];
  }
  __syncthreads();
  const float4* s4 = (const float4*)sout;
  float4* o4 = (float4*)(out + (size_t)n * (CCH * OHW));
  for (int q = c; q < (CCH * OHW) / 4; q += 256) o4[q] = s4[q];
}

extern "C" void kernel_launch(void* const* d_in, const int* in_sizes, int n_in,
                              void* d_out, int out_size, void* d_ws, size_t ws_size,
                              hipStream_t stream) {
  (void)n_in; (void)out_size;
  const float* feat = (const float*)d_in[0];
  const float* rois = (const float*)d_in[1];
  float* out = (float*)d_out;
  const int N = in_sizes[1] / 5;
  const int B = in_sizes[0] / (CCH * HH * WW);
  const size_t featbf_bytes = (size_t)in_sizes[0] * sizeof(unsigned short);
  const size_t meta_bytes   = (size_t)(16 + 2 * N) * sizeof(int);

  if (ws_size >= featbf_bytes + meta_bytes) {
    unsigned short* featbf = (unsigned short*)d_ws;
    int* meta = (int*)((char*)d_ws + featbf_bytes);
    const int use_perm = (B == 4 && (N & 7) == 0) ? 1 : 0;
    const int slots = N >> 2;                           // slots per batch

    ktrans_sched<<<dim3((HH * WW) / 64, CCH / 64, B + 1), dim3(256), 0, stream>>>(
        feat, featbf, rois, N, slots, use_perm, B, meta);
    roi_kernel16<<<dim3(N), dim3(512), 0, stream>>>(
        (const uint2*)featbf, rois, meta, N, use_perm, out);
  } else {
    roi_kernel_fb<<<dim3(N), dim3(256), 0, stream>>>(feat, rois, out);
  }
}

// Round 9
// 130.644 us; speedup vs baseline: 4.7528x; 1.0269x over previous
//
#include <hip/hip_runtime.h>
#include <cstdint>

// Problem constants: features (B=4, C=256, H=64, W=64) fp32,
// rois (N=2000, 5) fp32, output (N, C, 7, 7) fp32.
constexpr int CCH = 256;
constexpr int HH  = 64;
constexpr int WW  = 64;
constexpr int OHW = 49;
constexpr float RSCALE = 0.0625f;

// Bit-exact fp32 ops on the coordinate path (xs<64 validity test is the only
// discontinuity in the op).
#define FMUL __fmul_rn
#define FADD __fadd_rn
#define FSUB __fsub_rn
#define FDIV __fdiv_rn

typedef float     v4f __attribute__((ext_vector_type(4)));
typedef _Float16  h2  __attribute__((ext_vector_type(2)));
typedef _Float16  h4  __attribute__((ext_vector_type(4)));

__device__ __forceinline__ h2 pkrtz(float a, float b) {   // v_cvt_pkrtz_f16_f32
  auto t = __builtin_amdgcn_cvt_pkrtz(a, b);
  union { decltype(t) s; h2 d; } c; c.s = t; return c.d;
}
__device__ __forceinline__ h4 bcast4(float a) {           // (a,a,a,a) in fp16
  h2 t = pkrtz(a, a);
  return __builtin_shufflevector(t, t, 0, 1, 0, 1);
}
__device__ __forceinline__ h4 u2h(uint2 u) {              // reinterpret 4xfp16
  union { uint2 u; h4 h; } c; c.u = u; return c.h;
}
__device__ __forceinline__ h4 h4max(h4 a, h4 b) {         // 2x v_pk_max_f16
  return __builtin_elementwise_max(a, b);
}

// ---------------------------------------------------------------------------
// MEASURED CHAMPION (r2, 130.4 us). 8-round ledger: every subsequent
// intervention (persistence, VGPR relax, coop fusion, sw grid barriers,
// 1-block/roi) landed at +2.7..+3.8 or catastrophically worse. The timed
// region is fill (~64us, harness-fixed) + ktrans (~16us, 96MB BW floor) +
// roi (~20us, 100MB write floor + L2 gather latency) + launch residue.
// Kernel 1 (fused): transpose+quantize features (B,C,H*W) f32 -> (B,H*W,C)
// fp16 + roi scheduling pass as one extra grid slice (z==B, block (0,0)).
// Scheduling (XCD-batch affinity, 2 blocks/roi): roi block i -> XCD i%8;
// pair p=(i&7)>>1 gets batch-p rois so each XCD's gather set is one 2.1 MB
// fp16 slice (< 4 MiB XCD L2). slot s=i>>3.
// meta: [0..3]=cnt [4..7]=off [8..11]=cumslack; perm[N]; extra[N].
// ---------------------------------------------------------------------------
__global__ __launch_bounds__(256) void ktrans_sched(const float* __restrict__ in,
                                                    unsigned short* __restrict__ out,
                                                    const float* __restrict__ rois,
                                                    int N, int slots, int do_sched,
                                                    int B, int* __restrict__ meta) {
  const int t = threadIdx.x;

  if ((int)blockIdx.z == B) {
    if (blockIdx.x != 0 || blockIdx.y != 0 || !do_sched) return;
    __shared__ int cnt[4], rnk[4], off[4], slack[4], excess[4];
    if (t < 4) { cnt[t] = 0; rnk[t] = 0; }
    __syncthreads();
    for (int i = t; i < N; i += 256) atomicAdd(&cnt[(int)rois[i * 5]], 1);
    __syncthreads();
    if (t == 0) {
      int o = 0, cs = 0, ce = 0;
      for (int p = 0; p < 4; ++p) {
        off[p] = o; o += cnt[p];
        slack[p]  = cs; if (slots - cnt[p] > 0) cs += slots - cnt[p];
        excess[p] = ce; if (cnt[p] - slots > 0) ce += cnt[p] - slots;
        meta[p] = cnt[p]; meta[4 + p] = off[p]; meta[8 + p] = slack[p];
      }
    }
    __syncthreads();
    int* perm = meta + 16;
    for (int i = t; i < N; i += 256) {
      const int b = (int)rois[i * 5];
      perm[off[b] + atomicAdd(&rnk[b], 1)] = i;
    }
    __syncthreads();
    int* extra = meta + 16 + N;
    for (int p = 0; p < 4; ++p) {
      const int ex = cnt[p] - slots;
      for (int e = t; e < ex; e += 256) extra[excess[p] + e] = perm[off[p] + slots + e];
    }
    return;
  }

  __shared__ float tile[64][65];
  const int b  = blockIdx.z;
  const int c0 = blockIdx.y * 64;
  const int s0 = blockIdx.x * 64;
  const float* inb = in + (size_t)b * CCH * (HH * WW);
  unsigned short* outb = out + (size_t)b * (HH * WW) * CCH;

  const int cl = t >> 4, sq = t & 15;
#pragma unroll
  for (int k = 0; k < 4; ++k) {
    const int c = cl + 16 * k;
    const v4f v = __builtin_nontemporal_load(
        (const v4f*)(inb + (size_t)(c0 + c) * (HH * WW) + s0 + 4 * sq));
    tile[c][4 * sq + 0] = v[0];
    tile[c][4 * sq + 1] = v[1];
    tile[c][4 * sq + 2] = v[2];
    tile[c][4 * sq + 3] = v[3];
  }
  __syncthreads();
  const int cq = t & 15, rl = t >> 4;
#pragma unroll
  for (int k = 0; k < 4; ++k) {
    const int r = rl + 16 * k;
    union { h2 h; unsigned u; } p0, p1;
    p0.h.x = (_Float16)tile[4 * cq + 0][r];   // v_cvt_f16_f32 (RNE)
    p0.h.y = (_Float16)tile[4 * cq + 1][r];
    p1.h.x = (_Float16)tile[4 * cq + 2][r];
    p1.h.y = (_Float16)tile[4 * cq + 3][r];
    uint2 w; w.x = p0.u; w.y = p1.u;
    *(uint2*)(outb + (size_t)(s0 + r) * CCH + c0 + 4 * cq) = w;
  }
}

// ---------------------------------------------------------------------------
// Kernel 2 (r11 champion): RoIAlign + 2x2 s1 maxpool, packed-fp16 datapath.
//  - Gathered uint2 IS two half2 registers: interp = 8 v_pk_fma_f16 per q.
//    Weights computed in f32 (coord path bit-exact), single-rounded via
//    v_cvt_pkrtz broadcast.
//  - Maxpool + phase A/B in v_pk_max_f16 (monotone => quantize-before-max
//    exact); hc = 14 VGPR; A/B LDS traffic b64.
//  - Phase C scatters with immediate-offset ds_write_b16 into an fp16
//    out-linear LDS image; D is contiguous ds_read_b64 + 4 cvt +
//    nontemporal dwordx4 store.
//  - ldsA/ldsC DISJOINT 12,544 B regions: 2 barriers, no aliasing argument.
//    Total LDS 25,088 B -> 6 blocks/CU.
//  - Output stores nontemporal: 100 MB stream doesn't evict the 2.1 MB/XCD
//    fp16 feature slice from L2.
// ---------------------------------------------------------------------------
__global__ __launch_bounds__(256, 6) void roi_kernel11(const uint2* __restrict__ feat,
                                                       const float* __restrict__ rois,
                                                       const int* __restrict__ meta,
                                                       int N, int use_perm,
                                                       float* __restrict__ out) {
  __shared__ __attribute__((aligned(16))) h4       ldsA[OHW * 32];          // 12544 B
  __shared__ __attribute__((aligned(16))) _Float16 ldsC[(CCH / 2) * OHW];   // 12544 B
  const int i = blockIdx.x;
  const int t = threadIdx.x;
  const int g = t & 31;                        // granule within half (4 ch)
  const int r = t >> 5;                        // sample row 0..7

  int n, half;
  if (use_perm) {
    const int p = (i & 7) >> 1;
    half        = i & 1;
    const int s = i >> 3;
    const int c_ = meta[p];
    const int o_ = meta[4 + p];
    const int sl = meta[8 + p];
    const int* perm  = meta + 16;
    const int* extra = meta + 16 + N;
    n = (s < c_) ? perm[o_ + s] : extra[sl + (s - c_)];
  } else {
    n = i >> 1; half = i & 1;
  }

  const float rb = rois[n * 5 + 0];
  const float x1 = FMUL(rois[n * 5 + 1], RSCALE);
  const float y1 = FMUL(rois[n * 5 + 2], RSCALE);
  const float x2 = FMUL(rois[n * 5 + 3], RSCALE);
  const float y2 = FMUL(rois[n * 5 + 4], RSCALE);
  const int   b  = (int)rb;
  const float bh = FDIV(FSUB(y2, y1), 7.0f);
  const float bw = FDIV(FSUB(x2, x1), 7.0f);

  int   xo0[8], xo1[8];
  float lx[8];
  bool  xv[8];
#pragma unroll
  for (int q = 0; q < 8; ++q) {
    const float xs = FADD(x1, FMUL(bw, (float)q));
    xv[q] = (xs >= 0.0f) && (xs < (float)WW);
    const float xf = floorf(xs);
    lx[q] = FSUB(xs, xf);
    int a = (int)xf;
    a = a < 0 ? 0 : (a > WW - 1 ? WW - 1 : a);
    xo0[q] = a * (CCH / 4);
    xo1[q] = ((a + 1 > WW - 1) ? WW - 1 : a + 1) * (CCH / 4);
  }

  const float ys = FADD(y1, FMUL(bh, (float)r));
  const bool  yv = (ys >= 0.0f) && (ys < (float)HH);
  const float yf = floorf(ys);
  const float ly = FSUB(ys, yf);
  int d = (int)yf;
  d = d < 0 ? 0 : (d > HH - 1 ? HH - 1 : d);
  const int d1 = (d + 1 > HH - 1) ? HH - 1 : d + 1;

  const uint2* fb = feat + (size_t)b * (HH * WW) * (CCH / 4) + (half * 32 + g);
  const uint2* r0 = fb + (size_t)d  * (WW * (CCH / 4));
  const uint2* r1 = fb + (size_t)d1 * (WW * (CCH / 4));
  const float wy1 = ly, wy0 = 1.0f - ly;

  h4 hc[7], vprev;
#pragma unroll
  for (int h = 0; h < 2; ++h) {
    uint2 g00[4], g01[4], g10[4], g11[4];
#pragma unroll
    for (int q = 0; q < 4; ++q) {
      const int s = 4 * h + q;
      g00[q] = r0[xo0[s]];
      g01[q] = r0[xo1[s]];
      g10[q] = r1[xo0[s]];
      g11[q] = r1[xo1[s]];
    }
    h4 v[4];
#pragma unroll
    for (int q = 0; q < 4; ++q) {
      const int s = 4 * h + q;
      const bool ok = yv && xv[s];
      const float wx1 = lx[s], wx0 = 1.0f - wx1;
      const h4 w00 = bcast4(wy0 * wx0);        // f32 product, 1 rounding to fp16
      const h4 w01 = bcast4(wy0 * wx1);
      const h4 w10 = bcast4(wy1 * wx0);
      const h4 w11 = bcast4(wy1 * wx1);
      h4 rr = w00 * u2h(g00[q]) + w01 * u2h(g01[q])
            + w10 * u2h(g10[q]) + w11 * u2h(g11[q]);   // 8x v_pk_{mul,fma}_f16
      v[q] = ok ? rr : h4{};
    }
    if (h == 0) {
      hc[0] = h4max(v[0], v[1]);
      hc[1] = h4max(v[1], v[2]);
      hc[2] = h4max(v[2], v[3]);
      vprev = v[3];
    } else {
      hc[3] = h4max(vprev, v[0]);
      hc[4] = h4max(v[0], v[1]);
      hc[5] = h4max(v[1], v[2]);
      hc[6] = h4max(v[2], v[3]);
    }
  }

  // ---- phase A: row r>=1 publishes hc at slot r-1 (ds_write_b64) ----
  if (r >= 1) {
#pragma unroll
    for (int m = 0; m < 7; ++m)
      ldsA[((r - 1) * 7 + m) * 32 + g] = hc[m];
  }
  __syncthreads();                             // A->B: cross-wave publish

  // ---- phase B+C fused: row r<=6 maxes with row r+1's hc (b64 read +
  //      pk_max) and scatters the result into the fp16 out-linear image with
  //      immediate-offset ds_write_b16. ldsA/ldsC disjoint -> no barrier
  //      needed between B and C. ----
  if (r <= 6) {
    _Float16* cb = ldsC + (4 * g) * OHW + r * 7;   // channel 4g, out row r
#pragma unroll
    for (int m = 0; m < 7; ++m) {
      const h4 x = h4max(hc[m], ldsA[(r * 7 + m) * 32 + g]);
      cb[0 * OHW + m] = x[0];
      cb[1 * OHW + m] = x[1];
      cb[2 * OHW + m] = x[2];
      cb[3 * OHW + m] = x[3];
    }
  }
  __syncthreads();                             // C->D: cross-wave writeback

  // ---- phase D: contiguous b64 read -> 4x cvt -> nontemporal dwordx4.
  //      1568 float4 over 256 threads, no div/mod, no swizzle. ----
  const uint2* cs = (const uint2*)ldsC;
  v4f* o4 = (v4f*)(out + (size_t)n * (CCH * OHW) + half * (CCH / 2) * OHW);
#pragma unroll
  for (int m = 0; m < 7; ++m) {
    const int idx = m * 256 + t;
    if (idx < (CCH / 2) * OHW / 4) {
      const uint2 qv = cs[idx];
      union { unsigned u; h2 h; } c0, c1;
      c0.u = qv.x; c1.u = qv.y;
      v4f wv;
      wv.x = (float)c0.h.x;
      wv.y = (float)c0.h.y;
      wv.z = (float)c1.h.x;
      wv.w = (float)c1.h.y;
      __builtin_nontemporal_store(wv, o4 + idx);
    }
  }
}

// ---------------------------------------------------------------------------
// Fallback (workspace too small): round-2 scalar path, known-correct.
// ---------------------------------------------------------------------------
__global__ __launch_bounds__(256) void roi_kernel_fb(const float* __restrict__ feat,
                                                     const float* __restrict__ rois,
                                                     float* __restrict__ out) {
  __shared__ float sout[CCH * OHW];
  const int n = blockIdx.x;
  const int c = threadIdx.x;

  const float rb = rois[n * 5 + 0];
  const float x1 = FMUL(rois[n * 5 + 1], RSCALE);
  const float y1 = FMUL(rois[n * 5 + 2], RSCALE);
  const float x2 = FMUL(rois[n * 5 + 3], RSCALE);
  const float y2 = FMUL(rois[n * 5 + 4], RSCALE);
  const int b = (int)rb;
  const float bh = FDIV(FSUB(y2, y1), 7.0f);
  const float bw = FDIV(FSUB(x2, x1), 7.0f);

  int ix0[8], ix1[8], iy0[8], iy1[8];
  float lx[8], ly[8];
  bool xv[8], yv[8];
#pragma unroll
  for (int i = 0; i < 8; ++i) {
    const float xs = FADD(x1, FMUL(bw, (float)i));
    const float ys = FADD(y1, FMUL(bh, (float)i));
    xv[i] = (xs >= 0.0f) && (xs < (float)WW);
    yv[i] = (ys >= 0.0f) && (ys < (float)HH);
    const float xf = floorf(xs);
    const float yf = floorf(ys);
    lx[i] = FSUB(xs, xf);
    ly[i] = FSUB(ys, yf);
    int a = (int)xf;
    a = a < 0 ? 0 : (a > WW - 1 ? WW - 1 : a);
    ix0[i] = a;
    ix1[i] = (a + 1 > WW - 1) ? WW - 1 : a + 1;
    int d = (int)yf;
    d = d < 0 ? 0 : (d > HH - 1 ? HH - 1 : d);
    iy0[i] = d;
    iy1[i] = (d + 1 > HH - 1) ? HH - 1 : d + 1;
  }

  const float* fbp = feat + ((size_t)b * CCH + c) * (size_t)(HH * WW);
  float hp[7];
#pragma unroll
  for (int j = 0; j < 8; ++j) {
    float v[8];
    const float wy1 = ly[j], wy0 = 1.0f - ly[j];
#pragma unroll
    for (int i = 0; i < 8; ++i) {
      if (yv[j] && xv[i]) {
        const float f00 = fbp[iy0[j] * WW + ix0[i]];
        const float f01 = fbp[iy0[j] * WW + ix1[i]];
        const float f10 = fbp[iy1[j] * WW + ix0[i]];
        const float f11 = fbp[iy1[j] * WW + ix1[i]];
        const float wx1 = lx[i], wx0 = 1.0f - wx1;
        v[i] = wy0 * (wx0 * f00 + wx1 * f01) + wy1 * (wx0 * f10 + wx1 * f11);
      } else {
        v[i] = 0.0f;
      }
    }
    float hc[7];
#pragma unroll
    for (int i = 0; i < 7; ++i) hc[i] = fmaxf(v[i], v[i + 1]);
    if (j > 0) {
#pragma unroll
      for (int i = 0; i < 7; ++i)
        sout[c * OHW + (j - 1) * 7 + i] = fmaxf(hp[i], hc[i]);
    }
#pragma unroll
    for (int i = 0; i < 7; ++i) hp[i] = hc[i];
  }
  __syncthreads();
  const float4* s4 = (const float4*)sout;
  float4* o4 = (float4*)(out + (size_t)n * (CCH * OHW));
  for (int q = c; q < (CCH * OHW) / 4; q += 256) o4[q] = s4[q];
}

extern "C" void kernel_launch(void* const* d_in, const int* in_sizes, int n_in,
                              void* d_out, int out_size, void* d_ws, size_t ws_size,
                              hipStream_t stream) {
  (void)n_in; (void)out_size;
  const float* feat = (const float*)d_in[0];
  const float* rois = (const float*)d_in[1];
  float* out = (float*)d_out;
  const int N = in_sizes[1] / 5;
  const int B = in_sizes[0] / (CCH * HH * WW);
  const int M = 2 * N;                                  // roi blocks (2/roi)
  const size_t featbf_bytes = (size_t)in_sizes[0] * sizeof(unsigned short);
  const size_t meta_bytes   = (size_t)(16 + 2 * N) * sizeof(int);

  if (ws_size >= featbf_bytes + meta_bytes) {
    unsigned short* featbf = (unsigned short*)d_ws;
    int* meta = (int*)((char*)d_ws + featbf_bytes);
    const int use_perm = (B == 4 && (M & 7) == 0) ? 1 : 0;

    ktrans_sched<<<dim3((HH * WW) / 64, CCH / 64, B + 1), dim3(256), 0, stream>>>(
        feat, featbf, rois, N, M >> 3, use_perm, B, meta);
    roi_kernel11<<<dim3(M), dim3(256), 0, stream>>>(
        (const uint2*)featbf, rois, meta, N, use_perm, out);
  } else {
    roi_kernel_fb<<<dim3(N), dim3(256), 0, stream>>>(feat, rois, out);
  }
}